// Round 1
// baseline (177.158 us; speedup 1.0000x reference)
//
#include <hip/hip_runtime.h>
#include <hip/hip_bf16.h>

// Problem: weighted BCE over predict [N=8, C=19, H=512, W=1024] fp32 probs,
// target [N,H,W] int32 labels. Output: single fp32 scalar.
//
// result = (neg_num*S_pos + pos_num*S_neg) / ((pos_num+neg_num) * mask_cnt * C)
// where S_pos = sum over {mask & t>0} pixels of bce_pix, S_neg over {t==0},
// bce_pix = -sum_c log(clip((t==c) ? p_c : 1-p_c, 1e-12, 1)).

constexpr int   CLS    = 19;
constexpr int   HWSZ   = 512 * 1024;          // h*w, power of two
constexpr int   IGNORE = 255;
constexpr float LOGEPS = 1e-12f;

// ws layout (floats/uints interleaved in first 32 bytes):
// f[0]=S_pos, f[1]=S_neg, u[2]=pos_cnt, u[3]=neg_cnt, u[4]=mask_cnt

__global__ void bce_init(float* wsf) {
    // zero first 8 words of workspace
    if (threadIdx.x < 8) wsf[threadIdx.x] = 0.0f;
}

__global__ __launch_bounds__(256) void bce_main(
    const float* __restrict__ pred,
    const int*   __restrict__ tgt,
    float*       __restrict__ wsf,
    unsigned*    __restrict__ wsu,
    int n4)  // number of 4-pixel groups
{
    int tid    = blockIdx.x * blockDim.x + threadIdx.x;
    int stride = gridDim.x * blockDim.x;

    float    s_pos = 0.0f, s_neg = 0.0f;
    unsigned c_pos = 0, c_neg = 0, c_mask = 0;

    for (int i4 = tid; i4 < n4; i4 += stride) {
        int pix  = i4 << 2;                 // first pixel of the group
        int nimg = pix >> 19;               // pix / HWSZ
        int hw   = pix & (HWSZ - 1);

        int4 t4 = ((const int4*)tgt)[i4];
        int  t[4] = { t4.x, t4.y, t4.z, t4.w };

        const float* base = pred + (size_t)nimg * CLS * HWSZ + hw;

        float acc[4] = { 0.f, 0.f, 0.f, 0.f };
        #pragma unroll
        for (int c = 0; c < CLS; ++c) {
            float4 p4 = *(const float4*)(base + (size_t)c * HWSZ);
            float  p[4] = { p4.x, p4.y, p4.z, p4.w };
            #pragma unroll
            for (int j = 0; j < 4; ++j) {
                // select before log: one transcendental per element
                float x = (t[j] == c) ? p[j] : (1.0f - p[j]);
                x = fminf(fmaxf(x, LOGEPS), 1.0f);
                acc[j] += __logf(x);
            }
        }

        #pragma unroll
        for (int j = 0; j < 4; ++j) {
            int  tj   = t[j];
            bool pos  = tj > 0;
            bool neg  = tj == 0;
            bool mask = (tj >= 0) && (tj != IGNORE);
            float bce = -acc[j];
            c_pos  += pos ? 1u : 0u;
            c_neg  += neg ? 1u : 0u;
            c_mask += mask ? 1u : 0u;
            if (mask & pos) s_pos += bce;
            if (mask & neg) s_neg += bce;
        }
    }

    // ---- wave (64-lane) reduction ----
    #pragma unroll
    for (int off = 32; off > 0; off >>= 1) {
        s_pos  += __shfl_down(s_pos,  off);
        s_neg  += __shfl_down(s_neg,  off);
        c_pos  += __shfl_down(c_pos,  off);
        c_neg  += __shfl_down(c_neg,  off);
        c_mask += __shfl_down(c_mask, off);
    }

    // ---- block reduction across 4 waves ----
    __shared__ float    lsp[4], lsn[4];
    __shared__ unsigned lcp[4], lcn[4], lcm[4];
    int lane = threadIdx.x & 63;
    int wid  = threadIdx.x >> 6;
    if (lane == 0) {
        lsp[wid] = s_pos; lsn[wid] = s_neg;
        lcp[wid] = c_pos; lcn[wid] = c_neg; lcm[wid] = c_mask;
    }
    __syncthreads();
    if (threadIdx.x == 0) {
        float    bp = 0.f, bn = 0.f;
        unsigned up = 0, un = 0, um = 0;
        #pragma unroll
        for (int i = 0; i < 4; ++i) {
            bp += lsp[i]; bn += lsn[i];
            up += lcp[i]; un += lcn[i]; um += lcm[i];
        }
        atomicAdd(&wsf[0], bp);
        atomicAdd(&wsf[1], bn);
        atomicAdd(&wsu[2], up);
        atomicAdd(&wsu[3], un);
        atomicAdd(&wsu[4], um);
    }
}

__global__ void bce_final(const float* wsf, const unsigned* wsu, float* out) {
    if (threadIdx.x == 0 && blockIdx.x == 0) {
        double spos = (double)wsf[0];
        double sneg = (double)wsf[1];
        double pn   = (double)wsu[2];
        double nn   = (double)wsu[3];
        double mk   = (double)wsu[4];
        double sum  = pn + nn;
        double denom = sum * mk * (double)CLS;
        out[0] = (denom > 0.0) ? (float)((nn * spos + pn * sneg) / denom) : 0.0f;
    }
}

extern "C" void kernel_launch(void* const* d_in, const int* in_sizes, int n_in,
                              void* d_out, int out_size, void* d_ws, size_t ws_size,
                              hipStream_t stream) {
    const float* pred = (const float*)d_in[0];
    const int*   tgt  = (const int*)d_in[1];
    float*       out  = (float*)d_out;

    float*    wsf = (float*)d_ws;
    unsigned* wsu = (unsigned*)d_ws;

    int npix = in_sizes[1];     // n*h*w = 4194304
    int n4   = npix >> 2;       // 1048576 groups

    bce_init<<<1, 64, 0, stream>>>(wsf);

    int block = 256;
    int grid  = 2048;           // grid-stride; ~8 blocks/CU on 256 CUs
    bce_main<<<grid, block, 0, stream>>>(pred, tgt, wsf, wsu, n4);

    bce_final<<<1, 64, 0, stream>>>(wsf, wsu, out);
}